// Round 3
// baseline (122.436 us; speedup 1.0000x reference)
//
#include <hip/hip_runtime.h>
#include <hip/hip_bf16.h>

// ---------- types ----------
typedef __attribute__((ext_vector_type(8))) short bf16x8;   // 4 VGPR MFMA A/B frag
typedef __attribute__((ext_vector_type(4))) short bf16x4;   // 8B packed store
typedef __attribute__((ext_vector_type(4))) float f32x4;    // 4 VGPR MFMA C/D frag
typedef __attribute__((address_space(1))) const unsigned int gu32;
typedef __attribute__((address_space(3))) unsigned int lu32;

__device__ __forceinline__ unsigned short f2bf(float f) {
    __hip_bfloat16 h = __float2bfloat16(f);   // RNE
    return __builtin_bit_cast(unsigned short, h);
}

template<int N> __device__ __forceinline__ void waitv() {
    asm volatile("s_waitcnt vmcnt(%0)" :: "i"(N) : "memory");
}
__device__ __forceinline__ void waitlgkm0() {
    asm volatile("s_waitcnt lgkmcnt(0)" ::: "memory");
}

// Problem constants: B=16, C=768, H=W=48 -> HW=2304, tokens/mod = 36864
#define BT 64             // tokens per block
#define TPM 576           // tiles per modality = 36864/64
#define NCHUNK 24         // 768 / 32
#define DEPTH 4           // Fstage queue depth (pow2)

// ---------- precompute: partial u/v sums (u = g.W1 col-sums, v = b.W1) ----------
__global__ void prep_partial(const float* __restrict__ w1, const float* __restrict__ lng,
                             const float* __restrict__ lnb,
                             float* __restrict__ upart, float* __restrict__ vpart)
{
    const int m   = blockIdx.x >> 3;
    const int seg = blockIdx.x & 7;
    const int d   = threadIdx.x;          // 192 threads
    const float* w1m = w1 + (size_t)m * 768 * 192;
    const float* gm  = lng + m * 768;
    const float* bm  = lnb + m * 768;
    const int c0 = seg * 96;
    float su = 0.f, sv = 0.f;
    for (int c = 0; c < 96; ++c) {
        float wv = w1m[(size_t)(c0 + c) * 192 + d];
        su += gm[c0 + c] * wv;
        sv += bm[c0 + c] * wv;
    }
    upart[(m * 8 + seg) * 192 + d] = su;
    vpart[(m * 8 + seg) * 192 + d] = sv;
}

__global__ void prep_combine(const float* __restrict__ upart, const float* __restrict__ vpart,
                             const float* __restrict__ b1,
                             float* __restrict__ u, float* __restrict__ vb)
{
    const int m = blockIdx.x;
    const int d = threadIdx.x;            // 192 threads
    float su = 0.f, sv = 0.f;
    for (int s = 0; s < 8; ++s) {
        su += upart[(m * 8 + s) * 192 + d];
        sv += vpart[(m * 8 + s) * 192 + d];
    }
    u[m * 192 + d]  = su;
    vb[m * 192 + d] = sv + b1[m * 192 + d];
}

// ---------- precompute: pack g*W1 as bf16 in MFMA B-fragment order ----------
// w1f[m][kk(24)][nf(12)][lane(64)][8]; B-frag lane l holds B[k=(l>>4)*8+j][n=l&15].
__global__ void prep_pack(const float* __restrict__ w1, const float* __restrict__ lng,
                          unsigned short* __restrict__ w1f)
{
    const int m  = blockIdx.x / 24;
    const int kk = blockIdx.x % 24;
    const int tid = threadIdx.x;          // 256 threads
    __shared__ float ws[32 * 192];
    const float* w1m = w1 + ((size_t)m * 768 + kk * 32) * 192;
    const float* gm  = lng + m * 768 + kk * 32;
    for (int i = tid; i < 6144; i += 256) {
        int cl = i / 192, d = i % 192;
        ws[i] = gm[cl] * w1m[(size_t)cl * 192 + d];
    }
    __syncthreads();
    unsigned short* outp = w1f + ((size_t)m * 24 + kk) * 6144;
    for (int i = tid; i < 6144; i += 256) {
        int nf   = i >> 9;
        int rem  = i & 511;
        int lane = rem >> 3;
        int j    = rem & 7;
        int cl   = ((lane >> 4) << 3) + j;
        int d    = (nf << 4) + (lane & 15);
        outp[i]  = f2bf(ws[cl * 192 + d]);
    }
}

// ---------- fused main kernel ----------
// 256 thr (4 waves), 64 tokens/block. Wave w owns d-slice [w*48, w*48+48)
// (3 n-frags) over all 64 tokens (4 m-frags); loads channels [w*8, w*8+8).
//
// A-staging: global_load_lds (zero VGPR in flight) into Fstage[4][32][64] f32.
// Per step, per wave: 2 x gload_lds_dwordx4 (lane l -> ch l>>4, tokens 4(l&15)..+3;
// LDS = uniform base + lane*16 => [ch][tok] layout). Depth-4 queue: stage(k+4)
// issued after the mid-step barrier of step k (buffer (k&3) free: all pack reads
// of it retired before that barrier via each wave's lgkmcnt(0)).
//
// vmcnt arithmetic (pinned order: per step [STAGE(k+4)^2, LOADB(k+1)^3], prologue
// [S0 S1 S2 S3]^2 then B0^3; vmem retires in order):
//   top(0): after S0's last load: S1,S2,S3 (6) + B0 (3) = 9   -> vmcnt(9)
//   top(1): S2,S3,B0,S4,B1 = 12                               -> vmcnt(12)
//   top(2): S3,B0,S4,B1,S5,B2 = 15                            -> vmcnt(15)
//   top(k>=3): B(k-4),S(k+1),B(k-3),S(k+2),B(k-2),S(k+3),B(k-1) = 18 -> vmcnt(18)
// outstanding<=N with >=N younger ops  =>  stage(k) retired (in-order retire).
// Raw s_barrier only in the K-loop: global loads stay in flight across barriers.
__global__ __launch_bounds__(256, 3)
void fused_main(const float* __restrict__ f0, const float* __restrict__ f1,
                const float* __restrict__ f2,
                const unsigned short* __restrict__ w1f,
                const float* __restrict__ u_g, const float* __restrict__ vb_g,
                const float* __restrict__ w2_g, const float* __restrict__ b2_g,
                float* __restrict__ out)
{
    const int bx   = blockIdx.x;
    const int mod  = bx / TPM;
    const int tile = bx % TPM;
    const float* feat = (mod == 0) ? f0 : ((mod == 1) ? f1 : f2);
    const int T0   = tile * BT;
    const int bimg = T0 / 2304;
    const int hw0  = T0 % 2304;               // 64 | 2304: no image crossing
    const float* fbase = feat + (size_t)bimg * 768 * 2304 + hw0;

    const int tid = threadIdx.x;
    const int l   = tid & 63;
    const int w   = tid >> 6;     // wave 0..3
    const int p   = l & 31;       // token pair 2p, 2p+1 (pack phase)
    const int cg  = l >> 5;       // 4-ch half of this wave's 8-ch slot
    const int col = l & 15, lg = l >> 4;

    __shared__ float Fstage[DEPTH][32][64];      // 32 KB f32 staging queue
    __shared__ unsigned short Atile[64][40];     // 5 KB bf16, slot-XOR swizzle
    __shared__ float redS[4][64], redQ[4][64];
    __shared__ float mu_s[64], rs_s[64];
    __shared__ float red2[4][64];

    const unsigned short* w1fm = w1f + (size_t)mod * 24 * 6144;

    f32x4 acc[4][3];
    #pragma unroll
    for (int a = 0; a < 4; ++a)
        #pragma unroll
        for (int b = 0; b < 3; ++b) acc[a][b] = (f32x4){0.f, 0.f, 0.f, 0.f};

    float sum0 = 0.f, ssq0 = 0.f, sum1 = 0.f, ssq1 = 0.f;
    bf16x8 bf[3];

    auto STAGE = [&](int src_kk, int qb) {
        #pragma unroll
        for (int j = 0; j < 2; ++j) {
            const float* src = fbase + (size_t)(src_kk * 32 + w * 8 + j * 4 + lg) * 2304
                                     + 4 * (l & 15);
            __builtin_amdgcn_global_load_lds((gu32*)src,
                                             (lu32*)&Fstage[qb][w * 8 + j * 4][0],
                                             16, 0, 0);
        }
    };
    auto LOADB = [&](int kk) {
        const bf16x8* sB = reinterpret_cast<const bf16x8*>(w1fm + (size_t)kk * 6144);
        #pragma unroll
        for (int nf = 0; nf < 3; ++nf)
            bf[nf] = sB[(w * 3 + nf) * 64 + l];      // 16B/lane, L2-hot
    };
    auto TOPB = [&]() {
        __builtin_amdgcn_sched_barrier(0);
        __builtin_amdgcn_s_barrier();
        __builtin_amdgcn_sched_barrier(0);
    };

    auto STEPR = [&](int kk, int qb) {
        // ---- pack: Fstage[qb] (f32) -> stats + bf16 Atile ----
        const int t0 = 2 * p, t1 = t0 + 1;
        const int s0 = w ^ (((t0 >> 2) ^ (t0 >> 4)) & 3);
        const int s1 = w ^ (((t1 >> 2) ^ (t1 >> 4)) & 3);
        bf16x4 q0, q1;
        #pragma unroll
        for (int j = 0; j < 4; ++j) {
            float2 v = *reinterpret_cast<const float2*>(&Fstage[qb][w * 8 + cg * 4 + j][t0]);
            q0[j] = (short)f2bf(v.x);
            q1[j] = (short)f2bf(v.y);
            sum0 += v.x; ssq0 += v.x * v.x;
            sum1 += v.y; ssq1 += v.y * v.y;
        }
        *reinterpret_cast<bf16x4*>(&Atile[t0][s0 * 8 + cg * 4]) = q0;
        *reinterpret_cast<bf16x4*>(&Atile[t1][s1 * 8 + cg * 4]) = q1;
        waitlgkm0();
        TOPB();                                   // mid barrier: Atile ready, Fstage[qb] free
        int kn = kk + DEPTH; if (kn > NCHUNK - 1) kn = NCHUNK - 1;
        STAGE(kn, qb);                            // refill freed buffer (clamped: uniform counts)
        __builtin_amdgcn_sched_barrier(0);
        // ---- fragments + MFMA ----
        bf16x8 af[4];
        #pragma unroll
        for (int mf = 0; mf < 4; ++mf) {
            int t = mf * 16 + col;
            int s = lg ^ (((t >> 2) ^ (t >> 4)) & 3);
            af[mf] = *reinterpret_cast<const bf16x8*>(&Atile[t][s * 8]);
        }
        #pragma unroll
        for (int mf = 0; mf < 4; ++mf)
            #pragma unroll
            for (int nf = 0; nf < 3; ++nf)
                acc[mf][nf] = __builtin_amdgcn_mfma_f32_16x16x32_bf16(
                                  af[mf], bf[nf], acc[mf][nf], 0, 0, 0);
        int kb = kk + 1; if (kb > NCHUNK - 1) kb = NCHUNK - 1;
        LOADB(kb);                                // single-buffer B: WAR after MFMA
    };

    // ---- prologue: fill the queue ----
    STAGE(0, 0); STAGE(1, 1); STAGE(2, 2); STAGE(3, 3);
    __builtin_amdgcn_sched_barrier(0);
    LOADB(0);
    __builtin_amdgcn_sched_barrier(0);

    waitv<9>();  TOPB(); STEPR(0, 0);
    waitv<12>(); TOPB(); STEPR(1, 1);
    waitv<15>(); TOPB(); STEPR(2, 2);
    #pragma unroll 1
    for (int kk = 3; kk < NCHUNK; ++kk) {
        waitv<18>(); TOPB(); STEPR(kk, kk & 3);
    }

    // ---- LayerNorm stats (per token over all 768 ch) ----
    sum0 += __shfl_xor(sum0, 32);  sum1 += __shfl_xor(sum1, 32);
    ssq0 += __shfl_xor(ssq0, 32);  ssq1 += __shfl_xor(ssq1, 32);
    if (l < 32) {
        redS[w][2 * p] = sum0;  redS[w][2 * p + 1] = sum1;
        redQ[w][2 * p] = ssq0;  redQ[w][2 * p + 1] = ssq1;
    }
    __syncthreads();
    if (tid < 64) {
        float S = redS[0][tid] + redS[1][tid] + redS[2][tid] + redS[3][tid];
        float Q = redQ[0][tid] + redQ[1][tid] + redQ[2][tid] + redQ[3][tid];
        float mu = S * (1.f / 768.f);
        float var = Q * (1.f / 768.f) - mu * mu;
        mu_s[tid] = mu;
        rs_s[tid] = rsqrtf(var + 1e-5f);
    }
    __syncthreads();

    // ---- epilogue: affine LN fix + GELU + dot(w2) + sigmoid ----
    const float* um  = u_g  + mod * 192;
    const float* vbm = vb_g + mod * 192;
    const float* w2m = w2_g + mod * 192;
    float uf[3], vbf[3], w2f[3];
    #pragma unroll
    for (int nf = 0; nf < 3; ++nf) {
        int d = (w * 3 + nf) * 16 + col;
        uf[nf] = um[d]; vbf[nf] = vbm[d]; w2f[nf] = w2m[d];
    }
    float ps[4][4];
    #pragma unroll
    for (int mf = 0; mf < 4; ++mf) {
        #pragma unroll
        for (int r = 0; r < 4; ++r) {
            int t = mf * 16 + lg * 4 + r;   // C/D: row=(lane>>4)*4+reg
            float mu = mu_s[t], rs = rs_s[t];
            float pp = 0.f;
            #pragma unroll
            for (int nf = 0; nf < 3; ++nf) {
                float x = rs * (acc[mf][nf][r] - mu * uf[nf]) + vbf[nf];
                float h = 0.5f * x * (1.f + erff(x * 0.70710678118f));  // exact GELU
                pp += h * w2f[nf];
            }
            ps[mf][r] = pp;
        }
    }
    #pragma unroll
    for (int m = 1; m < 16; m <<= 1)
        #pragma unroll
        for (int mf = 0; mf < 4; ++mf)
            #pragma unroll
            for (int r = 0; r < 4; ++r)
                ps[mf][r] += __shfl_xor(ps[mf][r], m, 64);
    if (col == 0) {
        #pragma unroll
        for (int mf = 0; mf < 4; ++mf)
            #pragma unroll
            for (int r = 0; r < 4; ++r)
                red2[w][mf * 16 + lg * 4 + r] = ps[mf][r];
    }
    __syncthreads();
    if (tid < 64) {
        float logit = red2[0][tid] + red2[1][tid] + red2[2][tid] + red2[3][tid] + b2_g[mod];
        out[(size_t)mod * 36864 + T0 + tid] = 1.f / (1.f + expf(-logit));
    }
}

// ---------- launch ----------
extern "C" void kernel_launch(void* const* d_in, const int* in_sizes, int n_in,
                              void* d_out, int out_size, void* d_ws, size_t ws_size,
                              hipStream_t stream)
{
    const float* f0  = (const float*)d_in[0];
    const float* f1  = (const float*)d_in[1];
    const float* f2  = (const float*)d_in[2];
    const float* lng = (const float*)d_in[3];
    const float* lnb = (const float*)d_in[4];
    const float* w1  = (const float*)d_in[5];
    const float* b1  = (const float*)d_in[6];
    const float* w2  = (const float*)d_in[7];
    const float* b2  = (const float*)d_in[8];
    float* out = (float*)d_out;

    char* ws = (char*)d_ws;
    unsigned short* w1f = (unsigned short*)ws;          // 884736 B
    float* u     = (float*)(ws + 884736);               // 2304 B
    float* vb    = (float*)(ws + 887040);               // 2304 B
    float* upart = (float*)(ws + 889344);               // 18432 B
    float* vpart = (float*)(ws + 907776);               // 18432 B

    prep_partial<<<dim3(24), dim3(192), 0, stream>>>(w1, lng, lnb, upart, vpart);
    prep_combine<<<dim3(3),  dim3(192), 0, stream>>>(upart, vpart, b1, u, vb);
    prep_pack   <<<dim3(72), dim3(256), 0, stream>>>(w1, lng, w1f);
    fused_main  <<<dim3(3 * TPM), dim3(256), 0, stream>>>(f0, f1, f2, w1f, u, vb, w2, b2, out);
}